// Round 1
// baseline (2196.849 us; speedup 1.0000x reference)
//
#include <hip/hip_runtime.h>
#include <hip/hip_bf16.h>
#include <math.h>

#define D_MODEL 1024
#define N_HEADS 16
#define HEAD_DIM 64
#define D_FF 4096
#define N_LAYERS 4
#define VOCAB 2048
#define NUM_GROUPS 15
#define CACHE_LEN 17
#define EPS 1e-6f

__device__ __forceinline__ float wred(float v) {
#pragma unroll
  for (int o = 32; o > 0; o >>= 1) v += __shfl_xor(v, o, 64);
  return v;
}

// Block-cooperative rmsnorm scale for S rows of x (each block recomputes; x is
// tiny and L1/L2-hot, so redundant recompute beats a separate kernel+launch).
template <int NT>
__device__ __forceinline__ void block_rms_scale(const float* __restrict__ x, int S,
                                                float* s_scale, float* s_tmp) {
  for (int s = 0; s < S; ++s) {
    float p = 0.f;
    for (int j = threadIdx.x; j < D_MODEL; j += NT) {
      float v = x[s * D_MODEL + j];
      p += v * v;
    }
    p = wred(p);
    if ((threadIdx.x & 63) == 0) s_tmp[threadIdx.x >> 6] = p;
    __syncthreads();
    if (threadIdx.x == 0) {
      float t = 0.f;
#pragma unroll
      for (int w = 0; w < NT / 64; ++w) t += s_tmp[w];
      s_scale[s] = rsqrtf(t / (float)D_MODEL + EPS);
    }
    __syncthreads();
  }
}

// dot of two float4-vectorized arrays of length n4*256, reduced across the wave
__device__ __forceinline__ float dot_rows(const float4* __restrict__ w,
                                          const float4* __restrict__ v, int n4) {
  int lane = threadIdx.x & 63;
  float acc = 0.f;
  for (int it = 0; it < n4; ++it) {
    float4 a = w[it * 64 + lane];
    float4 b = v[it * 64 + lane];
    acc = fmaf(a.x, b.x, fmaf(a.y, b.y, fmaf(a.z, b.z, fmaf(a.w, b.w, acc))));
  }
  return wred(acc);
}

// dot of a 1024-length weight row against register-held hv[4]
__device__ __forceinline__ float dot_w_hv(const float* __restrict__ wrow,
                                          const float4 hv[4]) {
  int lane = threadIdx.x & 63;
  const float4* w = (const float4*)wrow;
  float acc = 0.f;
#pragma unroll
  for (int it = 0; it < 4; ++it) {
    float4 a = w[it * 64 + lane];
    acc = fmaf(a.x, hv[it].x, fmaf(a.y, hv[it].y, fmaf(a.z, hv[it].z, fmaf(a.w, hv[it].w, acc))));
  }
  return wred(acc);
}

__device__ __forceinline__ void load_hv(const float* __restrict__ x,
                                        const float* __restrict__ ln, float scale,
                                        float4 hv[4]) {
  int lane = threadIdx.x & 63;
  const float4* xv = (const float4*)x;
  const float4* lv = (const float4*)ln;
#pragma unroll
  for (int it = 0; it < 4; ++it) {
    float4 a = xv[it * 64 + lane];
    float4 b = lv[it * 64 + lane];
    hv[it] = make_float4(a.x * b.x * scale, a.y * b.y * scale, a.z * b.z * scale,
                         a.w * b.w * scale);
  }
}

// ---------------- kernels ----------------

__global__ void k_setup(const float* __restrict__ th, const float* __restrict__ c0,
                        float* __restrict__ x, float* __restrict__ esum) {
  int j = blockIdx.x * 256 + threadIdx.x;
  if (j < D_MODEL) {
    x[j] = th[j];
    x[D_MODEL + j] = c0[j];
    esum[j] = c0[j];
  }
}

// Fused rmsnorm + Q/K/V matvec + RoPE + KV cache write.
// grid 384 x 256: 1536 waves, one (matrix, even/odd output-pair) task each.
__global__ __launch_bounds__(256) void k_qkv(
    const float* __restrict__ x, const float* __restrict__ ln,
    const float* __restrict__ wq, const float* __restrict__ wk,
    const float* __restrict__ wv, float* __restrict__ qout,
    float* __restrict__ kcl, float* __restrict__ vcl, int S, int start) {
  __shared__ float s_scale[2];
  __shared__ float s_tmp[4];
  block_rms_scale<256>(x, S, s_scale, s_tmp);
  int lane = threadIdx.x & 63;
  int wid = blockIdx.x * 4 + (threadIdx.x >> 6);  // 0..1535
  int m = wid >> 9;                               // 0=q,1=k,2=v
  int p = wid & 511;                              // output pair index
  const float* W = (m == 0) ? wq : (m == 1) ? wk : wv;
  const float* w0 = W + (size_t)(2 * p) * D_MODEL;
  const float* w1 = w0 + D_MODEL;
  int h = (2 * p) >> 6;
  int dd = (2 * p) & 63;
  for (int s = 0; s < S; ++s) {
    float4 hv[4];
    load_hv(x + s * D_MODEL, ln, s_scale[s], hv);
    float d0 = dot_w_hv(w0, hv);
    float d1 = dot_w_hv(w1, hv);
    int pos = start + s;
    if (lane == 0) {
      if (m == 2) {
        vcl[(h * CACHE_LEN + pos) * HEAD_DIM + dd] = d0;
        vcl[(h * CACHE_LEN + pos) * HEAD_DIM + dd + 1] = d1;
      } else {
        int i = dd >> 1;
        float inv = powf(10000.f, -(float)(2 * i) / 64.f);
        float ang = (float)pos * inv;
        float c = cosf(ang), sn = sinf(ang);
        float o0 = d0 * c - d1 * sn;
        float o1 = d0 * sn + d1 * c;
        if (m == 0) {
          qout[s * D_MODEL + 2 * p] = o0;
          qout[s * D_MODEL + 2 * p + 1] = o1;
        } else {
          kcl[(h * CACHE_LEN + pos) * HEAD_DIM + dd] = o0;
          kcl[(h * CACHE_LEN + pos) * HEAD_DIM + dd + 1] = o1;
        }
      }
    }
  }
}

// one wave per head; scores over <=17 cached positions; softmax; PV.
__global__ __launch_bounds__(64) void k_attn(const float* __restrict__ q,
                                             const float* __restrict__ kcl,
                                             const float* __restrict__ vcl,
                                             float* __restrict__ attnb, int S,
                                             int start) {
  int h = blockIdx.x;
  int lane = threadIdx.x;
  __shared__ float sp[CACHE_LEN];
  for (int s = 0; s < S; ++s) {
    int pos = start + s;
    float qd = q[s * D_MODEL + h * HEAD_DIM + lane];
    for (int t = 0; t <= pos; ++t) {
      float prod = qd * kcl[(h * CACHE_LEN + t) * HEAD_DIM + lane];
      float sum = wred(prod);
      if (lane == 0) sp[t] = sum * 0.125f;  // 1/sqrt(64)
    }
    __syncthreads();
    if (lane == 0) {
      float mx = -1e30f;
      for (int t = 0; t <= pos; ++t) mx = fmaxf(mx, sp[t]);
      float sm = 0.f;
      for (int t = 0; t <= pos; ++t) {
        float e = expf(sp[t] - mx);
        sp[t] = e;
        sm += e;
      }
      float r = 1.f / sm;
      for (int t = 0; t <= pos; ++t) sp[t] *= r;
    }
    __syncthreads();
    float acc = 0.f;
    for (int t = 0; t <= pos; ++t)
      acc = fmaf(sp[t], vcl[(h * CACHE_LEN + t) * HEAD_DIM + lane], acc);
    attnb[s * D_MODEL + h * HEAD_DIM + lane] = acc;
    __syncthreads();
  }
}

// x += attn @ wo^T ; one wave per output row. grid 256 x 256.
__global__ __launch_bounds__(256) void k_wores(const float* __restrict__ attnb,
                                               const float* __restrict__ wo,
                                               float* __restrict__ x, int S) {
  int wid = blockIdx.x * 4 + (threadIdx.x >> 6);  // 0..1023
  const float4* wrow = (const float4*)(wo + (size_t)wid * D_MODEL);
  for (int s = 0; s < S; ++s) {
    float d = dot_rows(wrow, (const float4*)(attnb + s * D_MODEL), 4);
    if ((threadIdx.x & 63) == 0) x[s * D_MODEL + wid] += d;
  }
}

// rmsnorm + gate/up matvecs + silu*mul. grid 512 x 256 (2048 waves, 2 outputs each).
__global__ __launch_bounds__(256) void k_ffnup(const float* __restrict__ x,
                                               const float* __restrict__ ln,
                                               const float* __restrict__ w1,
                                               const float* __restrict__ w3,
                                               float* __restrict__ ff, int S) {
  __shared__ float s_scale[2];
  __shared__ float s_tmp[4];
  block_rms_scale<256>(x, S, s_scale, s_tmp);
  int lane = threadIdx.x & 63;
  int wid = blockIdx.x * 4 + (threadIdx.x >> 6);  // 0..2047
#pragma unroll
  for (int jj = 0; jj < 2; ++jj) {
    int j = wid + jj * 2048;
    const float* r1 = w1 + (size_t)j * D_MODEL;
    const float* r3 = w3 + (size_t)j * D_MODEL;
    for (int s = 0; s < S; ++s) {
      float4 hv[4];
      load_hv(x + s * D_MODEL, ln, s_scale[s], hv);
      float g = dot_w_hv(r1, hv);
      float u = dot_w_hv(r3, hv);
      if (lane == 0) ff[s * D_FF + j] = (g / (1.f + expf(-g))) * u;
    }
  }
}

// x += ff @ w2^T ; IN=4096. grid 256 x 256.
__global__ __launch_bounds__(256) void k_ffdown(const float* __restrict__ ff,
                                                const float* __restrict__ w2,
                                                float* __restrict__ x, int S) {
  int wid = blockIdx.x * 4 + (threadIdx.x >> 6);  // 0..1023
  const float4* wrow = (const float4*)(w2 + (size_t)wid * D_FF);
  for (int s = 0; s < S; ++s) {
    float d = dot_rows(wrow, (const float4*)(ff + s * D_FF), 16);
    if ((threadIdx.x & 63) == 0) x[s * D_MODEL + wid] += d;
  }
}

// logits = rmsnorm(x[row], lnf) @ head^T -> d_out slice + scratch. grid 512 x 256.
__global__ __launch_bounds__(256) void k_logits(const float* __restrict__ x, int row,
                                                const float* __restrict__ lnf,
                                                const float* __restrict__ head,
                                                float* __restrict__ out_g,
                                                float* __restrict__ lbuf) {
  __shared__ float s_scale[2];
  __shared__ float s_tmp[4];
  block_rms_scale<256>(x + row * D_MODEL, 1, s_scale, s_tmp);
  int lane = threadIdx.x & 63;
  int wid = blockIdx.x * 4 + (threadIdx.x >> 6);  // 0..2047
  float4 hv[4];
  load_hv(x + row * D_MODEL, lnf, s_scale[0], hv);
  float d = dot_w_hv(head + (size_t)wid * D_MODEL, hv);
  if (lane == 0) {
    out_g[wid] = d;
    lbuf[wid] = d;
  }
}

// single-block argmax (first-index tie-break, matches jnp.argmax) + embed gather
// + next-x write + embed_sum accumulate (+ final embed_sum store).
__global__ __launch_bounds__(256) void k_argmax_gather(
    const float* __restrict__ lbuf, const float* __restrict__ etab,
    float* __restrict__ x, float* __restrict__ esum, float* __restrict__ out_esum,
    int is_last) {
  __shared__ float bval[256];
  __shared__ int bidx[256];
  float best = -1e38f;
  int bi = 0;
  for (int j = threadIdx.x; j < VOCAB; j += 256) {
    float v = lbuf[j];
    if (v > best) {
      best = v;
      bi = j;
    }
  }
  bval[threadIdx.x] = best;
  bidx[threadIdx.x] = bi;
  __syncthreads();
  for (int off = 128; off > 0; off >>= 1) {
    if (threadIdx.x < off) {
      float v2 = bval[threadIdx.x + off];
      int i2 = bidx[threadIdx.x + off];
      float v1 = bval[threadIdx.x];
      int i1 = bidx[threadIdx.x];
      if (v2 > v1 || (v2 == v1 && i2 < i1)) {
        bval[threadIdx.x] = v2;
        bidx[threadIdx.x] = i2;
      }
    }
    __syncthreads();
  }
  int code = bidx[0];
  const float* emb = etab + (size_t)code * D_MODEL;
  for (int j = threadIdx.x; j < D_MODEL; j += 256) {
    float e = emb[j];
    x[j] = e;
    float ns = esum[j] + e;
    esum[j] = ns;
    if (is_last) out_esum[j] = ns;
  }
}

// ---------------- host ----------------

extern "C" void kernel_launch(void* const* d_in, const int* in_sizes, int n_in,
                              void* d_out, int out_size, void* d_ws, size_t ws_size,
                              hipStream_t stream) {
  const float* th = (const float*)d_in[0];
  const float* c0 = (const float*)d_in[1];
  const float* wq = (const float*)d_in[2];
  const float* wk = (const float*)d_in[3];
  const float* wv = (const float*)d_in[4];
  const float* wo = (const float*)d_in[5];
  const float* w1 = (const float*)d_in[6];
  const float* w2 = (const float*)d_in[7];
  const float* w3 = (const float*)d_in[8];
  const float* ln1 = (const float*)d_in[9];
  const float* ln2 = (const float*)d_in[10];
  const float* lnf = (const float*)d_in[11];
  const float* heads = (const float*)d_in[12];
  const float* embeds = (const float*)d_in[13];
  float* out = (float*)d_out;

  float* ws = (float*)d_ws;
  float* x = ws;              // 2048
  float* qb = ws + 2048;      // 2048
  float* attnb = ws + 4096;   // 2048
  float* ff = ws + 6144;      // 8192
  float* lbuf = ws + 14336;   // 2048
  float* esum = ws + 16384;   // 1024
  float* kc = ws + 17408;     // 69632
  float* vc = ws + 87040;     // 69632

  k_setup<<<4, 256, 0, stream>>>(th, c0, x, esum);

  auto run_layers = [&](int S, int start) {
    for (int l = 0; l < N_LAYERS; ++l) {
      const float* wq_l = wq + (size_t)l * D_MODEL * D_MODEL;
      const float* wk_l = wk + (size_t)l * D_MODEL * D_MODEL;
      const float* wv_l = wv + (size_t)l * D_MODEL * D_MODEL;
      const float* wo_l = wo + (size_t)l * D_MODEL * D_MODEL;
      const float* w1_l = w1 + (size_t)l * D_FF * D_MODEL;
      const float* w2_l = w2 + (size_t)l * D_MODEL * D_FF;
      const float* w3_l = w3 + (size_t)l * D_FF * D_MODEL;
      float* kcl = kc + (size_t)l * N_HEADS * CACHE_LEN * HEAD_DIM;
      float* vcl = vc + (size_t)l * N_HEADS * CACHE_LEN * HEAD_DIM;
      k_qkv<<<384, 256, 0, stream>>>(x, ln1 + l * D_MODEL, wq_l, wk_l, wv_l, qb, kcl,
                                     vcl, S, start);
      k_attn<<<16, 64, 0, stream>>>(qb, kcl, vcl, attnb, S, start);
      k_wores<<<256, 256, 0, stream>>>(attnb, wo_l, x, S);
      k_ffnup<<<512, 256, 0, stream>>>(x, ln2 + l * D_MODEL, w1_l, w3_l, ff, S);
      k_ffdown<<<256, 256, 0, stream>>>(ff, w2_l, x, S);
    }
  };

  // prefill: S=2, positions {0,1}
  run_layers(2, 0);

  for (int g = 0; g < NUM_GROUPS; ++g) {
    int row = (g == 0) ? 1 : 0;  // prefill hidden is row 1; later steps row 0
    k_logits<<<512, 256, 0, stream>>>(x, row, lnf, heads + (size_t)g * VOCAB * D_MODEL,
                                      out + (size_t)g * VOCAB, lbuf);
    k_argmax_gather<<<1, 256, 0, stream>>>(lbuf, embeds + (size_t)g * VOCAB * D_MODEL,
                                           x, esum, out + (size_t)NUM_GROUPS * VOCAB,
                                           g == NUM_GROUPS - 1);
    // the transformer step following the last argmax is dead (hidden unused)
    if (g < NUM_GROUPS - 1) run_layers(1, 2 + g);
  }
}

// Round 2
// 1922.118 us; speedup vs baseline: 1.1429x; 1.1429x over previous
//
#include <hip/hip_runtime.h>
#include <hip/hip_bf16.h>
#include <math.h>

#define D_MODEL 1024
#define N_HEADS 16
#define HEAD_DIM 64
#define D_FF 4096
#define N_LAYERS 4
#define VOCAB 2048
#define NUM_GROUPS 15
#define CACHE_LEN 17
#define EPS 1e-6f

typedef unsigned short ushort8v __attribute__((ext_vector_type(8)));

__device__ __forceinline__ float bf2f(unsigned short u) {
  union { unsigned int i; float f; } c;
  c.i = ((unsigned int)u) << 16;
  return c.f;
}

__device__ __forceinline__ unsigned short f2bf(float f) {
  union { float f; unsigned int i; } c;
  c.f = f;
  unsigned int r = (c.i + 0x7fffu + ((c.i >> 16) & 1u)) >> 16;
  return (unsigned short)r;
}

__device__ __forceinline__ float wred(float v) {
#pragma unroll
  for (int o = 32; o > 0; o >>= 1) v += __shfl_xor(v, o, 64);
  return v;
}

// Block-cooperative rmsnorm scale for S rows of x.
template <int NT>
__device__ __forceinline__ void block_rms_scale(const float* __restrict__ x, int S,
                                                float* s_scale, float* s_tmp) {
  for (int s = 0; s < S; ++s) {
    float p = 0.f;
    for (int j = threadIdx.x; j < D_MODEL; j += NT) {
      float v = x[s * D_MODEL + j];
      p += v * v;
    }
    p = wred(p);
    if ((threadIdx.x & 63) == 0) s_tmp[threadIdx.x >> 6] = p;
    __syncthreads();
    if (threadIdx.x == 0) {
      float t = 0.f;
#pragma unroll
      for (int w = 0; w < NT / 64; ++w) t += s_tmp[w];
      s_scale[s] = rsqrtf(t / (float)D_MODEL + EPS);
    }
    __syncthreads();
  }
}

// Activation layout for dots: lane covers elems {it*512 + lane*8 + c}, c=0..7.
template <int NIT>
__device__ __forceinline__ void load_act_scaled(const float* __restrict__ x,
                                                const float* __restrict__ ln,
                                                float scale, float* a) {
  int lane = threadIdx.x & 63;
  const float4* xv = (const float4*)x;
  const float4* lv = (const float4*)ln;
#pragma unroll
  for (int it = 0; it < NIT; ++it) {
    float4 v0 = xv[it * 128 + lane * 2];
    float4 v1 = xv[it * 128 + lane * 2 + 1];
    float4 l0 = lv[it * 128 + lane * 2];
    float4 l1 = lv[it * 128 + lane * 2 + 1];
    a[it * 8 + 0] = v0.x * l0.x * scale;
    a[it * 8 + 1] = v0.y * l0.y * scale;
    a[it * 8 + 2] = v0.z * l0.z * scale;
    a[it * 8 + 3] = v0.w * l0.w * scale;
    a[it * 8 + 4] = v1.x * l1.x * scale;
    a[it * 8 + 5] = v1.y * l1.y * scale;
    a[it * 8 + 6] = v1.z * l1.z * scale;
    a[it * 8 + 7] = v1.w * l1.w * scale;
  }
}

template <typename WT, int NIT>
__device__ __forceinline__ float dot_cached(const WT* __restrict__ wrow, const float* a) {
  int lane = threadIdx.x & 63;
  float acc = 0.f;
  if constexpr (sizeof(WT) == 2) {
    const ushort8v* w8 = (const ushort8v*)wrow;
#pragma unroll
    for (int it = 0; it < NIT; ++it) {
      ushort8v w = w8[it * 64 + lane];
#pragma unroll
      for (int c = 0; c < 8; ++c) acc = fmaf(bf2f(w[c]), a[it * 8 + c], acc);
    }
  } else {
    const float4* w4 = (const float4*)wrow;
#pragma unroll
    for (int it = 0; it < NIT; ++it) {
      float4 b0 = w4[it * 128 + lane * 2];
      float4 b1 = w4[it * 128 + lane * 2 + 1];
      acc = fmaf(b0.x, a[it * 8 + 0], acc);
      acc = fmaf(b0.y, a[it * 8 + 1], acc);
      acc = fmaf(b0.z, a[it * 8 + 2], acc);
      acc = fmaf(b0.w, a[it * 8 + 3], acc);
      acc = fmaf(b1.x, a[it * 8 + 4], acc);
      acc = fmaf(b1.y, a[it * 8 + 5], acc);
      acc = fmaf(b1.z, a[it * 8 + 6], acc);
      acc = fmaf(b1.w, a[it * 8 + 7], acc);
    }
  }
  return wred(acc);
}

template <typename WT, int NIT>
__device__ __forceinline__ float dot_stream(const WT* __restrict__ wrow,
                                            const float* __restrict__ act) {
  int lane = threadIdx.x & 63;
  const float4* av = (const float4*)act;
  float acc = 0.f;
  if constexpr (sizeof(WT) == 2) {
    const ushort8v* w8 = (const ushort8v*)wrow;
#pragma unroll
    for (int it = 0; it < NIT; ++it) {
      ushort8v w = w8[it * 64 + lane];
      float4 v0 = av[it * 128 + lane * 2];
      float4 v1 = av[it * 128 + lane * 2 + 1];
      acc = fmaf(bf2f(w[0]), v0.x, acc);
      acc = fmaf(bf2f(w[1]), v0.y, acc);
      acc = fmaf(bf2f(w[2]), v0.z, acc);
      acc = fmaf(bf2f(w[3]), v0.w, acc);
      acc = fmaf(bf2f(w[4]), v1.x, acc);
      acc = fmaf(bf2f(w[5]), v1.y, acc);
      acc = fmaf(bf2f(w[6]), v1.z, acc);
      acc = fmaf(bf2f(w[7]), v1.w, acc);
    }
  } else {
    const float4* w4 = (const float4*)wrow;
#pragma unroll
    for (int it = 0; it < NIT; ++it) {
      float4 b0 = w4[it * 128 + lane * 2];
      float4 b1 = w4[it * 128 + lane * 2 + 1];
      float4 v0 = av[it * 128 + lane * 2];
      float4 v1 = av[it * 128 + lane * 2 + 1];
      acc = fmaf(b0.x, v0.x, acc);
      acc = fmaf(b0.y, v0.y, acc);
      acc = fmaf(b0.z, v0.z, acc);
      acc = fmaf(b0.w, v0.w, acc);
      acc = fmaf(b1.x, v1.x, acc);
      acc = fmaf(b1.y, v1.y, acc);
      acc = fmaf(b1.z, v1.z, acc);
      acc = fmaf(b1.w, v1.w, acc);
    }
  }
  return wred(acc);
}

// ---------------- kernels ----------------

__global__ void k_convert(const float* __restrict__ src, unsigned short* __restrict__ dst,
                          size_t n8) {
  size_t stride = (size_t)gridDim.x * blockDim.x;
  const float4* s4 = (const float4*)src;
  ushort8v* d8 = (ushort8v*)dst;
  for (size_t i = (size_t)blockIdx.x * blockDim.x + threadIdx.x; i < n8; i += stride) {
    float4 a = s4[2 * i];
    float4 b = s4[2 * i + 1];
    ushort8v o;
    o[0] = f2bf(a.x); o[1] = f2bf(a.y); o[2] = f2bf(a.z); o[3] = f2bf(a.w);
    o[4] = f2bf(b.x); o[5] = f2bf(b.y); o[6] = f2bf(b.z); o[7] = f2bf(b.w);
    d8[i] = o;
  }
}

__global__ void k_setup(const float* __restrict__ th, const float* __restrict__ c0,
                        float* __restrict__ x, float* __restrict__ esum) {
  int j = blockIdx.x * 256 + threadIdx.x;
  if (j < D_MODEL) {
    x[j] = th[j];
    x[D_MODEL + j] = c0[j];
    esum[j] = c0[j];
  }
}

// Fused rmsnorm + Q/K/V matvec + RoPE + KV cache write. grid 384 x 256.
template <typename WT>
__global__ __launch_bounds__(256) void k_qkv(
    const float* __restrict__ x, const float* __restrict__ ln,
    const WT* __restrict__ wq, const WT* __restrict__ wk, const WT* __restrict__ wv,
    float* __restrict__ qout, float* __restrict__ kcl, float* __restrict__ vcl,
    int S, int start) {
  __shared__ float s_scale[2];
  __shared__ float s_tmp[4];
  block_rms_scale<256>(x, S, s_scale, s_tmp);
  int lane = threadIdx.x & 63;
  int wid = blockIdx.x * 4 + (threadIdx.x >> 6);  // 0..1535
  int m = wid >> 9;                               // 0=q,1=k,2=v
  int p = wid & 511;                              // output pair index
  const WT* W = (m == 0) ? wq : (m == 1) ? wk : wv;
  const WT* w0 = W + (size_t)(2 * p) * D_MODEL;
  const WT* w1 = w0 + D_MODEL;
  int h = (2 * p) >> 6;
  int dd = (2 * p) & 63;
  for (int s = 0; s < S; ++s) {
    float a[16];
    load_act_scaled<2>(x + s * D_MODEL, ln, s_scale[s], a);
    float d0 = dot_cached<WT, 2>(w0, a);
    float d1 = dot_cached<WT, 2>(w1, a);
    int pos = start + s;
    if (lane == 0) {
      if (m == 2) {
        vcl[(h * CACHE_LEN + pos) * HEAD_DIM + dd] = d0;
        vcl[(h * CACHE_LEN + pos) * HEAD_DIM + dd + 1] = d1;
      } else {
        int i = dd >> 1;
        float inv = powf(10000.f, -(float)(2 * i) / 64.f);
        float ang = (float)pos * inv;
        float c = cosf(ang), sn = sinf(ang);
        float o0 = d0 * c - d1 * sn;
        float o1 = d0 * sn + d1 * c;
        if (m == 0) {
          qout[s * D_MODEL + 2 * p] = o0;
          qout[s * D_MODEL + 2 * p + 1] = o1;
        } else {
          kcl[(h * CACHE_LEN + pos) * HEAD_DIM + dd] = o0;
          kcl[(h * CACHE_LEN + pos) * HEAD_DIM + dd + 1] = o1;
        }
      }
    }
  }
}

// one wave per head; scores over <=17 cached positions; softmax; PV.
__global__ __launch_bounds__(64) void k_attn(const float* __restrict__ q,
                                             const float* __restrict__ kcl,
                                             const float* __restrict__ vcl,
                                             float* __restrict__ attnb, int S,
                                             int start) {
  int h = blockIdx.x;
  int lane = threadIdx.x;
  __shared__ float sp[CACHE_LEN];
  for (int s = 0; s < S; ++s) {
    int pos = start + s;
    float qd = q[s * D_MODEL + h * HEAD_DIM + lane];
    for (int t = 0; t <= pos; ++t) {
      float prod = qd * kcl[(h * CACHE_LEN + t) * HEAD_DIM + lane];
      float sum = wred(prod);
      if (lane == 0) sp[t] = sum * 0.125f;  // 1/sqrt(64)
    }
    __syncthreads();
    if (lane == 0) {
      float mx = -1e30f;
      for (int t = 0; t <= pos; ++t) mx = fmaxf(mx, sp[t]);
      float sm = 0.f;
      for (int t = 0; t <= pos; ++t) {
        float e = expf(sp[t] - mx);
        sp[t] = e;
        sm += e;
      }
      float r = 1.f / sm;
      for (int t = 0; t <= pos; ++t) sp[t] *= r;
    }
    __syncthreads();
    float acc = 0.f;
    for (int t = 0; t <= pos; ++t)
      acc = fmaf(sp[t], vcl[(h * CACHE_LEN + t) * HEAD_DIM + lane], acc);
    attnb[s * D_MODEL + h * HEAD_DIM + lane] = acc;
    __syncthreads();
  }
}

// x += attn @ wo^T ; one wave per output row. grid 256 x 256.
template <typename WT>
__global__ __launch_bounds__(256) void k_wores(const float* __restrict__ attnb,
                                               const WT* __restrict__ wo,
                                               float* __restrict__ x, int S) {
  int wid = blockIdx.x * 4 + (threadIdx.x >> 6);  // 0..1023
  const WT* wrow = wo + (size_t)wid * D_MODEL;
  for (int s = 0; s < S; ++s) {
    float d = dot_stream<WT, 2>(wrow, attnb + s * D_MODEL);
    if ((threadIdx.x & 63) == 0) x[s * D_MODEL + wid] += d;
  }
}

// rmsnorm + gate/up matvecs + silu*mul. grid 512 x 256 (2048 waves, 2 outputs each).
template <typename WT>
__global__ __launch_bounds__(256) void k_ffnup(const float* __restrict__ x,
                                               const float* __restrict__ ln,
                                               const WT* __restrict__ w1,
                                               const WT* __restrict__ w3,
                                               float* __restrict__ ff, int S) {
  __shared__ float s_scale[2];
  __shared__ float s_tmp[4];
  block_rms_scale<256>(x, S, s_scale, s_tmp);
  int lane = threadIdx.x & 63;
  int wid = blockIdx.x * 4 + (threadIdx.x >> 6);  // 0..2047
  for (int s = 0; s < S; ++s) {
    float a[16];
    load_act_scaled<2>(x + s * D_MODEL, ln, s_scale[s], a);
#pragma unroll
    for (int jj = 0; jj < 2; ++jj) {
      int j = wid + jj * 2048;
      float g = dot_cached<WT, 2>(w1 + (size_t)j * D_MODEL, a);
      float u = dot_cached<WT, 2>(w3 + (size_t)j * D_MODEL, a);
      if (lane == 0) ff[s * D_FF + j] = (g / (1.f + expf(-g))) * u;
    }
  }
}

// x += ff @ w2^T ; IN=4096. grid 256 x 256.
template <typename WT>
__global__ __launch_bounds__(256) void k_ffdown(const float* __restrict__ ff,
                                                const WT* __restrict__ w2,
                                                float* __restrict__ x, int S) {
  int wid = blockIdx.x * 4 + (threadIdx.x >> 6);  // 0..1023
  const WT* wrow = w2 + (size_t)wid * D_FF;
  for (int s = 0; s < S; ++s) {
    float d = dot_stream<WT, 8>(wrow, ff + s * D_FF);
    if ((threadIdx.x & 63) == 0) x[s * D_MODEL + wid] += d;
  }
}

// logits = rmsnorm(x[row], lnf) @ head^T (heads stay f32). grid 512 x 256.
__global__ __launch_bounds__(256) void k_logits(const float* __restrict__ x, int row,
                                                const float* __restrict__ lnf,
                                                const float* __restrict__ head,
                                                float* __restrict__ out_g,
                                                float* __restrict__ lbuf) {
  __shared__ float s_scale[2];
  __shared__ float s_tmp[4];
  block_rms_scale<256>(x + row * D_MODEL, 1, s_scale, s_tmp);
  int lane = threadIdx.x & 63;
  int wid = blockIdx.x * 4 + (threadIdx.x >> 6);  // 0..2047
  float a[16];
  load_act_scaled<2>(x + row * D_MODEL, lnf, s_scale[0], a);
  float d = dot_cached<float, 2>(head + (size_t)wid * D_MODEL, a);
  if (lane == 0) {
    out_g[wid] = d;
    lbuf[wid] = d;
  }
}

// single-block argmax (first-index tie-break) + embed gather + next-x write +
// embed_sum accumulate (+ final embed_sum store).
__global__ __launch_bounds__(256) void k_argmax_gather(
    const float* __restrict__ lbuf, const float* __restrict__ etab,
    float* __restrict__ x, float* __restrict__ esum, float* __restrict__ out_esum,
    int is_last) {
  __shared__ float bval[256];
  __shared__ int bidx[256];
  float best = -1e38f;
  int bi = 0;
  for (int j = threadIdx.x; j < VOCAB; j += 256) {
    float v = lbuf[j];
    if (v > best) {
      best = v;
      bi = j;
    }
  }
  bval[threadIdx.x] = best;
  bidx[threadIdx.x] = bi;
  __syncthreads();
  for (int off = 128; off > 0; off >>= 1) {
    if (threadIdx.x < off) {
      float v2 = bval[threadIdx.x + off];
      int i2 = bidx[threadIdx.x + off];
      float v1 = bval[threadIdx.x];
      int i1 = bidx[threadIdx.x];
      if (v2 > v1 || (v2 == v1 && i2 < i1)) {
        bval[threadIdx.x] = v2;
        bidx[threadIdx.x] = i2;
      }
    }
    __syncthreads();
  }
  int code = bidx[0];
  const float* emb = etab + (size_t)code * D_MODEL;
  for (int j = threadIdx.x; j < D_MODEL; j += 256) {
    float e = emb[j];
    x[j] = e;
    float ns = esum[j] + e;
    esum[j] = ns;
    if (is_last) out_esum[j] = ns;
  }
}

// ---------------- host ----------------

template <typename WT>
static void run_model(const WT* wq, const WT* wk, const WT* wv, const WT* wo,
                      const WT* w1, const WT* w2, const WT* w3, const float* th,
                      const float* c0, const float* ln1, const float* ln2,
                      const float* lnf, const float* heads, const float* embeds,
                      float* out, float* fs, hipStream_t stream) {
  float* x = fs;              // 2048
  float* qb = fs + 2048;      // 2048
  float* attnb = fs + 4096;   // 2048
  float* ff = fs + 6144;      // 8192
  float* lbuf = fs + 14336;   // 2048
  float* esum = fs + 16384;   // 1024
  float* kc = fs + 17408;     // 69632
  float* vc = fs + 87040;     // 69632

  k_setup<<<4, 256, 0, stream>>>(th, c0, x, esum);

  auto run_layers = [&](int S, int start) {
    for (int l = 0; l < N_LAYERS; ++l) {
      const WT* wq_l = wq + (size_t)l * D_MODEL * D_MODEL;
      const WT* wk_l = wk + (size_t)l * D_MODEL * D_MODEL;
      const WT* wv_l = wv + (size_t)l * D_MODEL * D_MODEL;
      const WT* wo_l = wo + (size_t)l * D_MODEL * D_MODEL;
      const WT* w1_l = w1 + (size_t)l * D_FF * D_MODEL;
      const WT* w2_l = w2 + (size_t)l * D_MODEL * D_FF;
      const WT* w3_l = w3 + (size_t)l * D_FF * D_MODEL;
      float* kcl = kc + (size_t)l * N_HEADS * CACHE_LEN * HEAD_DIM;
      float* vcl = vc + (size_t)l * N_HEADS * CACHE_LEN * HEAD_DIM;
      k_qkv<WT><<<384, 256, 0, stream>>>(x, ln1 + l * D_MODEL, wq_l, wk_l, wv_l, qb,
                                         kcl, vcl, S, start);
      k_attn<<<16, 64, 0, stream>>>(qb, kcl, vcl, attnb, S, start);
      k_wores<WT><<<256, 256, 0, stream>>>(attnb, wo_l, x, S);
      k_ffnup<WT><<<512, 256, 0, stream>>>(x, ln2 + l * D_MODEL, w1_l, w3_l, ff, S);
      k_ffdown<WT><<<256, 256, 0, stream>>>(ff, w2_l, x, S);
    }
  };

  run_layers(2, 0);  // prefill: S=2, positions {0,1}

  for (int g = 0; g < NUM_GROUPS; ++g) {
    int row = (g == 0) ? 1 : 0;
    k_logits<<<512, 256, 0, stream>>>(x, row, lnf, heads + (size_t)g * VOCAB * D_MODEL,
                                      out + (size_t)g * VOCAB, lbuf);
    k_argmax_gather<<<1, 256, 0, stream>>>(lbuf, embeds + (size_t)g * VOCAB * D_MODEL,
                                           x, esum, out + (size_t)NUM_GROUPS * VOCAB,
                                           g == NUM_GROUPS - 1);
    if (g < NUM_GROUPS - 1) run_layers(1, 2 + g);
  }
}

extern "C" void kernel_launch(void* const* d_in, const int* in_sizes, int n_in,
                              void* d_out, int out_size, void* d_ws, size_t ws_size,
                              hipStream_t stream) {
  const float* th = (const float*)d_in[0];
  const float* c0 = (const float*)d_in[1];
  const float* wq = (const float*)d_in[2];
  const float* wk = (const float*)d_in[3];
  const float* wv = (const float*)d_in[4];
  const float* wo = (const float*)d_in[5];
  const float* w1 = (const float*)d_in[6];
  const float* w2 = (const float*)d_in[7];
  const float* w3 = (const float*)d_in[8];
  const float* ln1 = (const float*)d_in[9];
  const float* ln2 = (const float*)d_in[10];
  const float* lnf = (const float*)d_in[11];
  const float* heads = (const float*)d_in[12];
  const float* embeds = (const float*)d_in[13];
  float* out = (float*)d_out;

  const size_t QKVO = (size_t)N_LAYERS * D_MODEL * D_MODEL;  // 4M elems each
  const size_t FFW = (size_t)N_LAYERS * D_FF * D_MODEL;      // 16M elems each
  const size_t W_ELEMS = 4 * QKVO + 3 * FFW;                 // 64M
  const size_t SCRATCH_FLOATS = 156672;
  const size_t NEED = W_ELEMS * 2 + SCRATCH_FLOATS * 4;

  if (ws_size >= NEED) {
    unsigned short* wb = (unsigned short*)d_ws;
    unsigned short* bwq = wb;
    unsigned short* bwk = wb + QKVO;
    unsigned short* bwv = wb + 2 * QKVO;
    unsigned short* bwo = wb + 3 * QKVO;
    unsigned short* bw1 = wb + 4 * QKVO;
    unsigned short* bw3 = wb + 4 * QKVO + FFW;
    unsigned short* bw2 = wb + 4 * QKVO + 2 * FFW;
    float* fs = (float*)(wb + W_ELEMS);

    k_convert<<<2048, 256, 0, stream>>>(wq, bwq, QKVO / 8);
    k_convert<<<2048, 256, 0, stream>>>(wk, bwk, QKVO / 8);
    k_convert<<<2048, 256, 0, stream>>>(wv, bwv, QKVO / 8);
    k_convert<<<2048, 256, 0, stream>>>(wo, bwo, QKVO / 8);
    k_convert<<<2048, 256, 0, stream>>>(w1, bw1, FFW / 8);
    k_convert<<<2048, 256, 0, stream>>>(w3, bw3, FFW / 8);
    k_convert<<<2048, 256, 0, stream>>>(w2, bw2, FFW / 8);

    run_model<unsigned short>(bwq, bwk, bwv, bwo, bw1, bw2, bw3, th, c0, ln1, ln2,
                              lnf, heads, embeds, out, fs, stream);
  } else {
    float* fs = (float*)d_ws;
    run_model<float>(wq, wk, wv, wo, w1, w2, w3, th, c0, ln1, ln2, lnf, heads,
                     embeds, out, fs, stream);
  }
}